// Round 10
// baseline (345.312 us; speedup 1.0000x reference)
//
#include <hip/hip_runtime.h>

#define NN 100000
#define NE 600000
#define ET (NE + NN)
#define D 128
#define NREL 16
#define NB 98                    // dst buckets (dst>>10, 0..97)
#define NBIN (NREL * NB)         // 1568 edge bins; bin 1568 = self
#define NBL (NBIN + 1)           // 1569 logical bins
#define SCANB 391                // 391*256 = 100096 >= NN
#define TPB 4
#define MAXTILES 12544           // >= 600000/64 + 1568 + 1563
#define GEMMG ((MAXTILES + TPB - 1) / TPB)
#define WGRID 1088               // 17*16384/256

typedef short short8 __attribute__((ext_vector_type(8)));
typedef float f32x4 __attribute__((ext_vector_type(4)));
typedef unsigned int u32x4 __attribute__((ext_vector_type(4)));

// meta layout (ints)
#define C0 0                     // counts[1569]
#define O0 1570                  // offsets[1570]
#define CU0 3140                 // cursors[1569]
#define T0 4710                  // tileoff[1570]   (total 6280 ints)
#define META_BYTES 25600

// ws layout (bytes)
#define WT_OFF   0                 // 557056
#define META_OFF 557056            // 25600
#define DH_OFF   582656            // dstHist: 100000 ints (dead after scan1)
#define TI_OFF   582656            // tinfo int4[MAXTILES] ALIASES dstHist (200704 B)
#define DO_OFF   982656            // dstOff: 100001 ints (+pad)
#define DC_OFF   1382664           // dstCursor: 100000 ints
#define BS_OFF   1782664           // blockSums: 391 ints (+pad)
#define SSRC_OFF 1784712           // sSrc: ET ints
#define IDX_OFF  4584712           // idx: ET ints
#define SDST_OFF 7384712           // sDst (fallback only): ET ints
#define XB_OFF   10184712          // xb: 100000*128 bf16
#define MSG_OFF  35784712          // msg: ET*256 B
#define NEED_XB  (XB_OFF + (size_t)NN * D * 2)
#define NEED_MSG (MSG_OFF + (size_t)ET * 128 * 2)

__device__ __forceinline__ unsigned short f2bf(float f) {
  unsigned u = __builtin_bit_cast(unsigned, f);
  u += 0x7fffu + ((u >> 16) & 1u);   // RNE; inputs finite/normal
  return (unsigned short)(u >> 16);
}

// merged: [0,WGRID) wT; [WGRID,+12500) x->xb; last 256 blocks: histograms
__global__ __launch_bounds__(256) void k_ph(const float* __restrict__ bases,
    const float* __restrict__ coef, const float* __restrict__ w_self,
    unsigned short* __restrict__ wT, const float* __restrict__ x,
    unsigned short* __restrict__ xb, const int* __restrict__ ei,
    const int* __restrict__ et, int* __restrict__ meta, int* __restrict__ dstHist,
    int xbf, int doMsg)
{
  int bx = blockIdx.x;
  int tid = threadIdx.x;
  if (bx < WGRID) {
    int idx = bx * 256 + tid;   // < 17*16384
    int r = idx >> 14;
    int t = idx & 16383;
    float v;
    if (r < 16) {
      int o = t >> 7, i = t & 127;
      float acc = 0.f;
      #pragma unroll
      for (int b = 0; b < 8; ++b)
        acc += coef[r * 8 + b] * bases[b * 16384 + i * 128 + o];
      v = acc;
    } else {
      v = w_self[t];
    }
    wT[idx] = f2bf(v);
    return;
  }
  int hb0 = WGRID + (xbf ? 12500 : 0);
  if (bx < hb0) {
    int i = (bx - WGRID) * 256 + tid;
    if (i >= NN * D / 4) return;
    f32x4 f = __builtin_nontemporal_load((const f32x4*)(x + (size_t)i * 4));
    unsigned short s0 = f2bf(f[0]), s1 = f2bf(f[1]), s2 = f2bf(f[2]), s3 = f2bf(f[3]);
    unsigned long long pk = (unsigned long long)s0 | ((unsigned long long)s1 << 16)
                          | ((unsigned long long)s2 << 32) | ((unsigned long long)s3 << 48);
    *(unsigned long long*)(xb + (size_t)i * 4) = pk;
    return;
  }
  // histogram blocks (256): (rel,bucket) bins + dst histogram
  __shared__ int h[NBIN];
  int hb = bx - hb0;
  for (int i = tid; i < NBIN; i += 256) h[i] = 0;
  __syncthreads();
  for (int e = hb * 256 + tid; e < NE; e += 256 * 256) {
    int dst = ei[e];
    atomicAdd(&h[et[e] * NB + (dst >> 10)], 1);
    if (doMsg) atomicAdd(&dstHist[dst], 1);
  }
  __syncthreads();
  for (int i = tid; i < NBIN; i += 256)
    if (h[i]) atomicAdd(&meta[C0 + i], h[i]);
}

__global__ __launch_bounds__(256) void k_scan1(const int* __restrict__ dstHist,
    int* __restrict__ dstOff, int* __restrict__ blockSums)
{
  __shared__ int sh[256];
  int tid = threadIdx.x;
  int d = blockIdx.x * 256 + tid;
  int v = (d < NN) ? (dstHist[d] + 1) : 0;   // +1: virtual self edge
  sh[tid] = v;
  __syncthreads();
  #pragma unroll
  for (int ofs = 1; ofs < 256; ofs <<= 1) {
    int t = (tid >= ofs) ? sh[tid - ofs] : 0;
    __syncthreads();
    sh[tid] += t;
    __syncthreads();
  }
  if (d < NN) dstOff[d] = sh[tid] - v;
  if (tid == 255) blockSums[blockIdx.x] = sh[tid];
}

// phase A: blockSums scan (1024-wide); phase B: 1569-bin scan (2 bins/thread)
__global__ __launch_bounds__(1024) void k_scan2(int* __restrict__ blockSums,
    int* __restrict__ meta, int doMsg)
{
  __shared__ int sA[1024];
  __shared__ int sB[1024];
  int tid = threadIdx.x;

  if (doMsg) {
    int v = (tid < SCANB) ? blockSums[tid] : 0;
    sA[tid] = v;
    __syncthreads();
    #pragma unroll
    for (int ofs = 1; ofs < 1024; ofs <<= 1) {
      int t = (tid >= ofs) ? sA[tid - ofs] : 0;
      __syncthreads();
      sA[tid] += t;
      __syncthreads();
    }
    if (tid < SCANB) blockSums[tid] = sA[tid] - v;   // exclusive
    __syncthreads();
  }

  // phase B: bins (i = 2t, 2t+1), scan both row-offsets and tile-offsets
  int i0 = tid * 2, i1 = tid * 2 + 1;
  int c0 = (i0 < NBIN) ? meta[C0 + i0] : ((i0 == NBIN) ? NN : 0);
  int c1 = (i1 < NBIN) ? meta[C0 + i1] : ((i1 == NBIN) ? NN : 0);
  int t0 = (c0 + 63) >> 6, t1 = (c1 + 63) >> 6;
  sA[tid] = c0 + c1;
  sB[tid] = t0 + t1;
  __syncthreads();
  #pragma unroll
  for (int ofs = 1; ofs < 1024; ofs <<= 1) {
    int a = (tid >= ofs) ? sA[tid - ofs] : 0;
    int b = (tid >= ofs) ? sB[tid - ofs] : 0;
    __syncthreads();
    sA[tid] += a;
    sB[tid] += b;
    __syncthreads();
  }
  int offEx = sA[tid] - (c0 + c1);
  int tEx = sB[tid] - (t0 + t1);
  if (i0 < NBL) {
    meta[O0 + i0] = offEx;
    meta[T0 + i0] = tEx;
    if (i0 < NBIN) meta[CU0 + i0] = offEx;
    meta[C0 + i0] = c0;   // persist self count too
  }
  if (i1 < NBL) {
    meta[O0 + i1] = offEx + c0;
    meta[T0 + i1] = tEx + t0;
    if (i1 < NBIN) meta[CU0 + i1] = offEx + c0;
    meta[C0 + i1] = c1;
  }
  if (tid == 1023) {
    meta[O0 + NBL] = sA[tid];
    meta[T0 + NBL] = sB[tid];
  }
}

// finalize dstOff; cursor past self slot; self: msg row NE+d
__global__ __launch_bounds__(256) void k_scan3(int* __restrict__ dstOff,
    const int* __restrict__ blockSums, int* __restrict__ dstCursor,
    int* __restrict__ sSrc, int* __restrict__ idx)
{
  int tid = threadIdx.x;
  int d = blockIdx.x * 256 + tid;
  int base = blockSums[blockIdx.x];
  if (d < NN) {
    int o = dstOff[d] + base;
    dstOff[d] = o;
    dstCursor[d] = o + 1;
    idx[o] = NE + d;
    sSrc[NE + d] = d;
  }
  if (d == NN) dstOff[NN] = ET;
}

__global__ __launch_bounds__(256) void k_selfF(int* __restrict__ sSrc, int* __restrict__ sDst)
{
  int n = blockIdx.x * 256 + threadIdx.x;
  if (n < NN) { sSrc[NE + n] = n; sDst[NE + n] = n; }
}

// per-tile metadata: binary search over T0[0..NBL] -> {e0, nrows, rel}
__global__ __launch_bounds__(256) void k_tinfo(const int* __restrict__ meta,
    int4* __restrict__ tinfo)
{
  int t = blockIdx.x * 256 + threadIdx.x;
  if (t >= MAXTILES) return;
  int ntiles = meta[T0 + NBL];
  if (t >= ntiles) { tinfo[t] = make_int4(0, 0, 0, 0); return; }
  int lo = 0, hi = NBL;
  while (lo < hi) {
    int mid = (lo + hi + 1) >> 1;
    if (meta[T0 + mid] <= t) lo = mid; else hi = mid - 1;
  }
  int bin = lo;
  int e0 = meta[O0 + bin] + (t - meta[T0 + bin]) * 64;
  int nr = min(64, meta[O0 + bin + 1] - e0);
  int rel = (bin < NBIN) ? (bin / NB) : 16;
  tinfo[t] = make_int4(e0, nr, rel, 0);
}

// (rel,dstBucket) bins. doMsg: idx[dstSlot]=pos (positions now bucket-local).
__global__ __launch_bounds__(256) void k_scatter(const int* __restrict__ ei, const int* __restrict__ et,
    int* __restrict__ meta, int* __restrict__ sSrc, int* __restrict__ sDst,
    int* __restrict__ dstCursor, int* __restrict__ idx, int doMsg)
{
  __shared__ int h[NBIN], base[NBIN], lh[NBIN];
  int tid = threadIdx.x;
  int start = blockIdx.x * 4096;
  int end = min(NE, start + 4096);
  for (int i = tid; i < NBIN; i += 256) { h[i] = 0; lh[i] = 0; }
  __syncthreads();
  for (int e = start + tid; e < end; e += 256)
    atomicAdd(&h[et[e] * NB + (ei[e] >> 10)], 1);
  __syncthreads();
  for (int i = tid; i < NBIN; i += 256)
    if (h[i]) base[i] = atomicAdd(&meta[CU0 + i], h[i]);
  __syncthreads();
  for (int e = start + tid; e < end; e += 256) {
    int row = ei[e];
    int bin = et[e] * NB + (row >> 10);
    int pos = base[bin] + atomicAdd(&lh[bin], 1);
    sSrc[pos] = ei[NE + e];
    if (doMsg) idx[atomicAdd(&dstCursor[row], 1)] = pos;
    else sDst[pos] = row;
  }
}

// TPB tiles/block, full __syncthreads (R9-validated). msg written in bin order
// (pos=e0+row): sequential stores. Reads for one dst-bucket confined to 16
// ~100KB windows -> k_reduce gathers are L2-local.
__global__ __launch_bounds__(256) void k_gemm(const float* __restrict__ xf,
    const unsigned short* __restrict__ xb,
    const unsigned short* __restrict__ wT, const int* __restrict__ meta,
    const int* __restrict__ sSrc, const int* __restrict__ sDst,
    const int4* __restrict__ tinfo,
    unsigned short* __restrict__ msg, float* __restrict__ out,
    int xbf, int msgmode)
{
  __shared__ short As[64 * 17 * 8];
  __shared__ short Es[64 * 136];
  __shared__ int Rows[64];

  int tid = threadIdx.x;
  int ntiles = meta[T0 + NBL];
  int b0 = blockIdx.x * TPB;
  if (b0 >= ntiles) return;

  int lane = tid & 63, wave = tid >> 6;
  int q = lane >> 4, l15 = lane & 15;
  int m = tid >> 2, ug = tid & 3;

  int rprev = -1;
  short8 bfr[2][4];

  if (xbf && msgmode) {
    for (int ti = 0; ti < TPB; ++ti) {
      int b = b0 + ti;
      if (b >= ntiles) break;
      int4 ifo = tinfo[b];
      int e0 = ifo.x, nr = ifo.y, r = ifo.z;

      bool valid = m < nr;
      int src = sSrc[valid ? (e0 + m) : e0];
      const unsigned short* xr = xb + (size_t)src * 128;
      #pragma unroll
      for (int s = 0; s < 4; ++s) {
        int u = ug * 4 + s;
        short8 pk = (short8)(short)0;
        if (valid) pk = *(const short8*)(xr + u * 8);
        *(short8*)&As[(m * 17 + u) * 8] = pk;
      }
      __syncthreads();   // As visible

      if (r != rprev) {
        const unsigned short* wr = wT + r * 16384;
        #pragma unroll
        for (int ns = 0; ns < 2; ++ns)
          #pragma unroll
          for (int kk = 0; kk < 4; ++kk)
            bfr[ns][kk] = *(const short8*)(wr + (wave * 32 + ns * 16 + l15) * 128 + kk * 32 + q * 8);
        rprev = r;
      }

      f32x4 acc[4][2];
      #pragma unroll
      for (int ms = 0; ms < 4; ++ms)
        #pragma unroll
        for (int ns = 0; ns < 2; ++ns)
          acc[ms][ns] = (f32x4){0.f, 0.f, 0.f, 0.f};
      #pragma unroll
      for (int kk = 0; kk < 4; ++kk) {
        short8 af[4];
        #pragma unroll
        for (int ms = 0; ms < 4; ++ms)
          af[ms] = *(const short8*)&As[((ms * 16 + l15) * 17 + kk * 4 + q) * 8];
        #pragma unroll
        for (int ms = 0; ms < 4; ++ms)
          #pragma unroll
          for (int ns = 0; ns < 2; ++ns)
            acc[ms][ns] = __builtin_amdgcn_mfma_f32_16x16x32_bf16(af[ms], bfr[ns][kk], acc[ms][ns], 0, 0, 0);
      }

      __syncthreads();   // As reads drained
      #pragma unroll
      for (int ms = 0; ms < 4; ++ms)
        #pragma unroll
        for (int ns = 0; ns < 2; ++ns)
          #pragma unroll
          for (int reg = 0; reg < 4; ++reg)
            Es[(ms * 16 + q * 4 + reg) * 136 + wave * 32 + ns * 16 + l15] =
                (short)f2bf(acc[ms][ns][reg]);
      __syncthreads();   // Es visible

      #pragma unroll
      for (int i = 0; i < 4; ++i) {
        int row = wave * 16 + i * 4 + q;
        short8 v = *(const short8*)&Es[row * 136 + l15 * 8];
        if (row < nr)
          *(short8*)(msg + (size_t)(e0 + row) * 128 + l15 * 8) = v;
      }
      __syncthreads();   // Es reads drained
    }
    return;
  }

  // ---------------- generic fallback (atomic out) ----------------
  for (int ti = 0; ti < TPB; ++ti) {
    int b = b0 + ti;
    if (b >= ntiles) break;
    int4 ifo = tinfo[b];
    int e0 = ifo.x, nrows = ifo.y, r = ifo.z;

    bool valid = m < nrows;
    int e = valid ? (e0 + m) : e0;
    int src = sSrc[e];
    if (ug == 0) Rows[m] = valid ? sDst[e] : 0;

    if (xbf) {
      const unsigned short* xr = xb + (size_t)src * 128;
      #pragma unroll
      for (int s = 0; s < 4; ++s) {
        int u = ug * 4 + s;
        short8 pk = (short8)(short)0;
        if (valid) pk = *(const short8*)(xr + u * 8);
        *(short8*)&As[(m * 17 + u) * 8] = pk;
      }
    } else {
      const float* xr = xf + (size_t)src * 128;
      #pragma unroll
      for (int s = 0; s < 4; ++s) {
        int u = ug * 4 + s;
        float4 f0 = make_float4(0.f, 0.f, 0.f, 0.f), f1 = f0;
        if (valid) {
          f0 = *(const float4*)(xr + u * 8);
          f1 = *(const float4*)(xr + u * 8 + 4);
        }
        short8 pk;
        pk[0] = (short)f2bf(f0.x); pk[1] = (short)f2bf(f0.y);
        pk[2] = (short)f2bf(f0.z); pk[3] = (short)f2bf(f0.w);
        pk[4] = (short)f2bf(f1.x); pk[5] = (short)f2bf(f1.y);
        pk[6] = (short)f2bf(f1.z); pk[7] = (short)f2bf(f1.w);
        *(short8*)&As[(m * 17 + u) * 8] = pk;
      }
    }
    __syncthreads();

    if (r != rprev) {
      const unsigned short* wr = wT + r * 16384;
      #pragma unroll
      for (int ns = 0; ns < 2; ++ns)
        #pragma unroll
        for (int kk = 0; kk < 4; ++kk)
          bfr[ns][kk] = *(const short8*)(wr + (wave * 32 + ns * 16 + l15) * 128 + kk * 32 + q * 8);
      rprev = r;
    }

    f32x4 acc[4][2];
    #pragma unroll
    for (int ms = 0; ms < 4; ++ms)
      #pragma unroll
      for (int ns = 0; ns < 2; ++ns)
        acc[ms][ns] = (f32x4){0.f, 0.f, 0.f, 0.f};
    #pragma unroll
    for (int kk = 0; kk < 4; ++kk) {
      short8 af[4];
      #pragma unroll
      for (int ms = 0; ms < 4; ++ms)
        af[ms] = *(const short8*)&As[((ms * 16 + l15) * 17 + kk * 4 + q) * 8];
      #pragma unroll
      for (int ms = 0; ms < 4; ++ms)
        #pragma unroll
        for (int ns = 0; ns < 2; ++ns)
          acc[ms][ns] = __builtin_amdgcn_mfma_f32_16x16x32_bf16(af[ms], bfr[ns][kk], acc[ms][ns], 0, 0, 0);
    }

    __syncthreads();
    #pragma unroll
    for (int ms = 0; ms < 4; ++ms)
      #pragma unroll
      for (int reg = 0; reg < 4; ++reg) {
        int mrow = ms * 16 + q * 4 + reg;
        if (mrow < nrows) {
          float* op = out + (size_t)Rows[mrow] * 128 + wave * 32 + l15;
          unsafeAtomicAdd(op, acc[ms][0][reg]);
          unsafeAtomicAdd(op + 16, acc[ms][1][reg]);
        }
      }
    __syncthreads();
  }
}

// one 16-lane group per dst: idx-indirect gather (bucket-local), fp32 accumulate
__global__ __launch_bounds__(256) void k_reduce(const unsigned short* __restrict__ msg,
    const int* __restrict__ dstOff, const int* __restrict__ idx,
    float* __restrict__ out)
{
  int d = blockIdx.x * 16 + (threadIdx.x >> 4);
  if (d >= NN) return;
  int sl = threadIdx.x & 15;
  int s = dstOff[d], e = dstOff[d + 1];
  const unsigned short* base = msg + (size_t)sl * 8;
  float a[8], bacc[8];
  #pragma unroll
  for (int i = 0; i < 8; ++i) { a[i] = 0.f; bacc[i] = 0.f; }
  int j = s;
  for (; j + 1 < e; j += 2) {
    size_t p0 = (size_t)idx[j] * 128;
    size_t p1 = (size_t)idx[j + 1] * 128;
    u32x4 v0 = *(const u32x4*)(base + p0);
    u32x4 v1 = *(const u32x4*)(base + p1);
    #pragma unroll
    for (int c = 0; c < 4; ++c) {
      a[2 * c]     += __builtin_bit_cast(float, v0[c] << 16);
      a[2 * c + 1] += __builtin_bit_cast(float, v0[c] & 0xffff0000u);
      bacc[2 * c]     += __builtin_bit_cast(float, v1[c] << 16);
      bacc[2 * c + 1] += __builtin_bit_cast(float, v1[c] & 0xffff0000u);
    }
  }
  if (j < e) {
    u32x4 v0 = *(const u32x4*)(base + (size_t)idx[j] * 128);
    #pragma unroll
    for (int c = 0; c < 4; ++c) {
      a[2 * c]     += __builtin_bit_cast(float, v0[c] << 16);
      a[2 * c + 1] += __builtin_bit_cast(float, v0[c] & 0xffff0000u);
    }
  }
  f32x4 w0, w1;
  w0[0] = a[0] + bacc[0]; w0[1] = a[1] + bacc[1]; w0[2] = a[2] + bacc[2]; w0[3] = a[3] + bacc[3];
  w1[0] = a[4] + bacc[4]; w1[1] = a[5] + bacc[5]; w1[2] = a[6] + bacc[6]; w1[3] = a[7] + bacc[7];
  float* op = out + (size_t)d * 128 + sl * 8;
  __builtin_nontemporal_store(w0, (f32x4*)op);
  __builtin_nontemporal_store(w1, (f32x4*)(op + 4));
}

extern "C" void kernel_launch(void* const* d_in, const int* in_sizes, int n_in,
                              void* d_out, int out_size, void* d_ws, size_t ws_size,
                              hipStream_t stream)
{
  const float* x      = (const float*)d_in[0];
  const int*   ei     = (const int*)d_in[1];
  const int*   et     = (const int*)d_in[2];
  const float* bases  = (const float*)d_in[3];
  const float* coef   = (const float*)d_in[4];
  const float* w_self = (const float*)d_in[5];
  float* out = (float*)d_out;
  char* ws = (char*)d_ws;
  unsigned short* wT = (unsigned short*)(ws + WT_OFF);
  int* meta      = (int*)(ws + META_OFF);
  int* dstHist   = (int*)(ws + DH_OFF);
  int4* tinfo    = (int4*)(ws + TI_OFF);     // aliases dstHist (dead after scan1)
  int* dstOff    = (int*)(ws + DO_OFF);
  int* dstCursor = (int*)(ws + DC_OFF);
  int* blockSums = (int*)(ws + BS_OFF);
  int* sSrc      = (int*)(ws + SSRC_OFF);
  int* idx       = (int*)(ws + IDX_OFF);
  int* sDst      = (int*)(ws + SDST_OFF);
  unsigned short* xb = (unsigned short*)(ws + XB_OFF);
  unsigned short* msg = (unsigned short*)(ws + MSG_OFF);

  const int msgmode = (ws_size >= NEED_MSG) ? 1 : 0;
  const int xbf = (msgmode || ws_size >= NEED_XB) ? 1 : 0;

  hipMemsetAsync(ws + META_OFF, 0, META_BYTES + 400000, stream);  // meta + dstHist
  k_ph<<<WGRID + (xbf ? 12500 : 0) + 256, 256, 0, stream>>>(
      bases, coef, w_self, wT, x, xb, ei, et, meta, dstHist, xbf, msgmode);
  if (msgmode) {
    k_scan1<<<SCANB, 256, 0, stream>>>(dstHist, dstOff, blockSums);
    k_scan2<<<1, 1024, 0, stream>>>(blockSums, meta, 1);
    k_scan3<<<SCANB, 256, 0, stream>>>(dstOff, blockSums, dstCursor, sSrc, idx);
  } else {
    k_scan2<<<1, 1024, 0, stream>>>(blockSums, meta, 0);
    k_selfF<<<SCANB, 256, 0, stream>>>(sSrc, sDst);
    hipMemsetAsync(d_out, 0, (size_t)NN * D * 4, stream);
  }
  k_scatter<<<(NE + 4095) / 4096, 256, 0, stream>>>(ei, et, meta, sSrc, sDst, dstCursor, idx, msgmode);
  k_tinfo<<<(MAXTILES + 255) / 256, 256, 0, stream>>>(meta, tinfo);
  k_gemm<<<GEMMG, 256, 0, stream>>>(x, xb, wT, meta, sSrc, sDst, tinfo, msg, out, xbf, msgmode);
  if (msgmode)
    k_reduce<<<(NN + 15) / 16, 256, 0, stream>>>(msg, dstOff, idx, out);
}

// Round 11
// 336.830 us; speedup vs baseline: 1.0252x; 1.0252x over previous
//
#include <hip/hip_runtime.h>

#define NN 100000
#define NE 600000
#define ET (NE + NN)
#define D 128
#define NREL 16
#define BSH 11                   // bucket shift
#define BSZ 2048                 // dsts per bucket
#define NB 49                    // buckets (100000/2048 -> 49)
#define BPB 17                   // bins per bucket: 16 rel + self
#define NBIN (NB * BPB)          // 833
#define SCANB 391                // 391*256 = 100096 >= NN
#define TPB 4
#define MAXTILES 12544
#define GEMMG ((MAXTILES + TPB - 1) / TPB)
#define SCATB ((NE + 4095) / 4096)          // 147
#define TIB ((MAXTILES + 255) / 256)        // 49
#define WGRID 1088               // 17*16384/256

typedef short short8 __attribute__((ext_vector_type(8)));
typedef float f32x4 __attribute__((ext_vector_type(4)));
typedef unsigned int u32x4 __attribute__((ext_vector_type(4)));

// meta layout (ints)
#define C0 0                     // counts[833]
#define O0 840                   // offsets[834]
#define CU0 1680                 // cursors[833]
#define T0 2520                  // tileoff[834]
#define META_BYTES 13568

// ws layout (bytes)
#define WT_OFF   0                 // 557056
#define META_OFF 557056            // 13568
#define DH_OFF   570624            // dstHist: 100000 ints (dead after scan1)
#define TI_OFF   570624            // tinfo int4[MAXTILES] ALIASES dstHist
#define DO_OFF   970624            // dstOff: 100001 ints (+pad)
#define DC_OFF   1370640           // dstCursor: 100000 ints
#define BS_OFF   1770640           // blockSums: 391 ints (+pad)
#define SSRC_OFF 1772688           // sSrc: ET ints
#define IDX_OFF  4572688           // idx: ET ints
#define SDST_OFF 7372688           // sDst (fallback only): ET ints
#define XB_OFF   10172688          // xb: 100000*128 bf16
#define MSG_OFF  35772688          // msg: ET*256 B
#define NEED_XB  (XB_OFF + (size_t)NN * D * 2)
#define NEED_MSG (MSG_OFF + (size_t)ET * 128 * 2)

__device__ __forceinline__ unsigned short f2bf(float f) {
  unsigned u = __builtin_bit_cast(unsigned, f);
  u += 0x7fffu + ((u >> 16) & 1u);   // RNE; inputs finite/normal
  return (unsigned short)(u >> 16);
}

// merged: [0,WGRID) wT; [WGRID,+12500) x->xb; last 256 blocks: histograms
__global__ __launch_bounds__(256) void k_ph(const float* __restrict__ bases,
    const float* __restrict__ coef, const float* __restrict__ w_self,
    unsigned short* __restrict__ wT, const float* __restrict__ x,
    unsigned short* __restrict__ xb, const int* __restrict__ ei,
    const int* __restrict__ et, int* __restrict__ meta, int* __restrict__ dstHist,
    int xbf, int doMsg)
{
  int bx = blockIdx.x;
  int tid = threadIdx.x;
  if (bx < WGRID) {
    int idx = bx * 256 + tid;   // < 17*16384
    int r = idx >> 14;
    int t = idx & 16383;
    float v;
    if (r < 16) {
      int o = t >> 7, i = t & 127;
      float acc = 0.f;
      #pragma unroll
      for (int b = 0; b < 8; ++b)
        acc += coef[r * 8 + b] * bases[b * 16384 + i * 128 + o];
      v = acc;
    } else {
      v = w_self[t];
    }
    wT[idx] = f2bf(v);
    return;
  }
  int hb0 = WGRID + (xbf ? 12500 : 0);
  if (bx < hb0) {
    int i = (bx - WGRID) * 256 + tid;
    if (i >= NN * D / 4) return;
    f32x4 f = __builtin_nontemporal_load((const f32x4*)(x + (size_t)i * 4));
    unsigned short s0 = f2bf(f[0]), s1 = f2bf(f[1]), s2 = f2bf(f[2]), s3 = f2bf(f[3]);
    unsigned long long pk = (unsigned long long)s0 | ((unsigned long long)s1 << 16)
                          | ((unsigned long long)s2 << 32) | ((unsigned long long)s3 << 48);
    *(unsigned long long*)(xb + (size_t)i * 4) = pk;
    return;
  }
  // histogram blocks (256): (bucket,rel) bins + dst histogram
  __shared__ int h[NBIN];
  int hb = bx - hb0;
  for (int i = tid; i < NBIN; i += 256) h[i] = 0;
  __syncthreads();
  for (int e = hb * 256 + tid; e < NE; e += 256 * 256) {
    int dst = ei[e];
    atomicAdd(&h[(dst >> BSH) * BPB + et[e]], 1);
    if (doMsg) atomicAdd(&dstHist[dst], 1);
  }
  __syncthreads();
  for (int i = tid; i < NBIN; i += 256)
    if (h[i]) atomicAdd(&meta[C0 + i], h[i]);
}

__global__ __launch_bounds__(256) void k_scan1(const int* __restrict__ dstHist,
    int* __restrict__ dstOff, int* __restrict__ blockSums)
{
  __shared__ int sh[256];
  int tid = threadIdx.x;
  int d = blockIdx.x * 256 + tid;
  int v = (d < NN) ? (dstHist[d] + 1) : 0;   // +1: virtual self edge
  sh[tid] = v;
  __syncthreads();
  #pragma unroll
  for (int ofs = 1; ofs < 256; ofs <<= 1) {
    int t = (tid >= ofs) ? sh[tid - ofs] : 0;
    __syncthreads();
    sh[tid] += t;
    __syncthreads();
  }
  if (d < NN) dstOff[d] = sh[tid] - v;
  if (tid == 255) blockSums[blockIdx.x] = sh[tid];
}

// phase A (doMsg): blockSums scan; phase B: 833-bin scan (rows + tiles), self counts static
__global__ __launch_bounds__(1024) void k_scan2(int* __restrict__ blockSums,
    int* __restrict__ meta, int doMsg)
{
  __shared__ int sA[1024];
  __shared__ int sB[1024];
  int tid = threadIdx.x;

  if (doMsg) {
    int v = (tid < SCANB) ? blockSums[tid] : 0;
    sA[tid] = v;
    __syncthreads();
    #pragma unroll
    for (int ofs = 1; ofs < 1024; ofs <<= 1) {
      int t = (tid >= ofs) ? sA[tid - ofs] : 0;
      __syncthreads();
      sA[tid] += t;
      __syncthreads();
    }
    if (tid < SCANB) blockSums[tid] = sA[tid] - v;   // exclusive
    __syncthreads();
  }

  int c = 0;
  if (tid < NBIN) {
    int rel = tid % BPB;
    if (rel == 16) c = min(BSZ, NN - (tid / BPB) * BSZ);   // self bin: static count
    else c = meta[C0 + tid];
  }
  int t = (c + 63) >> 6;
  sA[tid] = c;
  sB[tid] = t;
  __syncthreads();
  #pragma unroll
  for (int ofs = 1; ofs < 1024; ofs <<= 1) {
    int a = (tid >= ofs) ? sA[tid - ofs] : 0;
    int b = (tid >= ofs) ? sB[tid - ofs] : 0;
    __syncthreads();
    sA[tid] += a;
    sB[tid] += b;
    __syncthreads();
  }
  int offEx = sA[tid] - c;
  int tEx = sB[tid] - t;
  if (tid <= NBIN) {
    meta[O0 + tid] = offEx;
    meta[T0 + tid] = tEx;
    if (tid < NBIN) meta[CU0 + tid] = offEx;
  }
}

// finalize dstOff; cursor past self slot; self row lives INSIDE its bucket window
__global__ __launch_bounds__(256) void k_scan3(int* __restrict__ dstOff,
    const int* __restrict__ blockSums, int* __restrict__ dstCursor,
    int* __restrict__ sSrc, int* __restrict__ idx, const int* __restrict__ meta)
{
  int tid = threadIdx.x;
  int d = blockIdx.x * 256 + tid;
  int base = blockSums[blockIdx.x];
  if (d < NN) {
    int o = dstOff[d] + base;
    dstOff[d] = o;
    dstCursor[d] = o + 1;
    int bkt = d >> BSH;
    int selfPos = meta[O0 + bkt * BPB + 16] + (d & (BSZ - 1));
    idx[o] = selfPos;
    sSrc[selfPos] = d;
  }
  if (d == NN) dstOff[NN] = ET;
}

__global__ __launch_bounds__(256) void k_selfF(int* __restrict__ sSrc, int* __restrict__ sDst,
    const int* __restrict__ meta)
{
  int n = blockIdx.x * 256 + threadIdx.x;
  if (n < NN) {
    int bkt = n >> BSH;
    int selfPos = meta[O0 + bkt * BPB + 16] + (n & (BSZ - 1));
    sSrc[selfPos] = n;
    sDst[selfPos] = n;
  }
}

// blocks [0,SCATB): (bucket,rel) bin scatter; blocks [SCATB,SCATB+TIB): tinfo
__global__ __launch_bounds__(256) void k_scatter(const int* __restrict__ ei, const int* __restrict__ et,
    int* __restrict__ meta, int* __restrict__ sSrc, int* __restrict__ sDst,
    int* __restrict__ dstCursor, int* __restrict__ idx, int4* __restrict__ tinfo,
    int doMsg)
{
  __shared__ int h[NBIN], base[NBIN], lh[NBIN];
  int tid = threadIdx.x;
  int bx = blockIdx.x;

  if (bx >= SCATB) {
    // tinfo: binary search T0[0..NBIN] -> {e0, nrows, rel}
    int t = (bx - SCATB) * 256 + tid;
    if (t >= MAXTILES) return;
    int ntiles = meta[T0 + NBIN];
    if (t >= ntiles) { tinfo[t] = make_int4(0, 0, 0, 0); return; }
    int lo = 0, hi = NBIN;
    while (lo < hi) {
      int mid = (lo + hi + 1) >> 1;
      if (meta[T0 + mid] <= t) lo = mid; else hi = mid - 1;
    }
    int bin = lo;
    int e0 = meta[O0 + bin] + (t - meta[T0 + bin]) * 64;
    int nr = min(64, meta[O0 + bin + 1] - e0);
    tinfo[t] = make_int4(e0, nr, bin % BPB, 0);
    return;
  }

  int start = bx * 4096;
  int end = min(NE, start + 4096);
  for (int i = tid; i < NBIN; i += 256) { h[i] = 0; lh[i] = 0; }
  __syncthreads();
  for (int e = start + tid; e < end; e += 256)
    atomicAdd(&h[(ei[e] >> BSH) * BPB + et[e]], 1);
  __syncthreads();
  for (int i = tid; i < NBIN; i += 256)
    if (h[i]) base[i] = atomicAdd(&meta[CU0 + i], h[i]);
  __syncthreads();
  for (int e = start + tid; e < end; e += 256) {
    int row = ei[e];
    int bin = (row >> BSH) * BPB + et[e];
    int pos = base[bin] + atomicAdd(&lh[bin], 1);
    sSrc[pos] = ei[NE + e];
    if (doMsg) idx[atomicAdd(&dstCursor[row], 1)] = pos;
    else sDst[pos] = row;
  }
}

// TPB tiles/block, full __syncthreads (R9/R10-validated). msg written in bin order
// (pos=e0+row): sequential stores. One bucket's msg (16 rels + self) = ONE
// contiguous ~3.7MB region -> k_reduce's gathers are window-local.
__global__ __launch_bounds__(256) void k_gemm(const float* __restrict__ xf,
    const unsigned short* __restrict__ xb,
    const unsigned short* __restrict__ wT, const int* __restrict__ meta,
    const int* __restrict__ sSrc, const int* __restrict__ sDst,
    const int4* __restrict__ tinfo,
    unsigned short* __restrict__ msg, float* __restrict__ out,
    int xbf, int msgmode)
{
  __shared__ short As[64 * 17 * 8];
  __shared__ short Es[64 * 136];
  __shared__ int Rows[64];

  int tid = threadIdx.x;
  int ntiles = meta[T0 + NBIN];
  int b0 = blockIdx.x * TPB;
  if (b0 >= ntiles) return;

  int lane = tid & 63, wave = tid >> 6;
  int q = lane >> 4, l15 = lane & 15;
  int m = tid >> 2, ug = tid & 3;

  int rprev = -1;
  short8 bfr[2][4];

  if (xbf && msgmode) {
    for (int ti = 0; ti < TPB; ++ti) {
      int b = b0 + ti;
      if (b >= ntiles) break;
      int4 ifo = tinfo[b];
      int e0 = ifo.x, nr = ifo.y, r = ifo.z;

      bool valid = m < nr;
      int src = sSrc[valid ? (e0 + m) : e0];
      const unsigned short* xr = xb + (size_t)src * 128;
      #pragma unroll
      for (int s = 0; s < 4; ++s) {
        int u = ug * 4 + s;
        short8 pk = (short8)(short)0;
        if (valid) pk = *(const short8*)(xr + u * 8);
        *(short8*)&As[(m * 17 + u) * 8] = pk;
      }
      __syncthreads();   // As visible

      if (r != rprev) {
        const unsigned short* wr = wT + r * 16384;
        #pragma unroll
        for (int ns = 0; ns < 2; ++ns)
          #pragma unroll
          for (int kk = 0; kk < 4; ++kk)
            bfr[ns][kk] = *(const short8*)(wr + (wave * 32 + ns * 16 + l15) * 128 + kk * 32 + q * 8);
        rprev = r;
      }

      f32x4 acc[4][2];
      #pragma unroll
      for (int ms = 0; ms < 4; ++ms)
        #pragma unroll
        for (int ns = 0; ns < 2; ++ns)
          acc[ms][ns] = (f32x4){0.f, 0.f, 0.f, 0.f};
      #pragma unroll
      for (int kk = 0; kk < 4; ++kk) {
        short8 af[4];
        #pragma unroll
        for (int ms = 0; ms < 4; ++ms)
          af[ms] = *(const short8*)&As[((ms * 16 + l15) * 17 + kk * 4 + q) * 8];
        #pragma unroll
        for (int ms = 0; ms < 4; ++ms)
          #pragma unroll
          for (int ns = 0; ns < 2; ++ns)
            acc[ms][ns] = __builtin_amdgcn_mfma_f32_16x16x32_bf16(af[ms], bfr[ns][kk], acc[ms][ns], 0, 0, 0);
      }

      __syncthreads();   // As reads drained
      #pragma unroll
      for (int ms = 0; ms < 4; ++ms)
        #pragma unroll
        for (int ns = 0; ns < 2; ++ns)
          #pragma unroll
          for (int reg = 0; reg < 4; ++reg)
            Es[(ms * 16 + q * 4 + reg) * 136 + wave * 32 + ns * 16 + l15] =
                (short)f2bf(acc[ms][ns][reg]);
      __syncthreads();   // Es visible

      #pragma unroll
      for (int i = 0; i < 4; ++i) {
        int row = wave * 16 + i * 4 + q;
        short8 v = *(const short8*)&Es[row * 136 + l15 * 8];
        if (row < nr)
          *(short8*)(msg + (size_t)(e0 + row) * 128 + l15 * 8) = v;
      }
      __syncthreads();   // Es reads drained
    }
    return;
  }

  // ---------------- generic fallback (atomic out) ----------------
  for (int ti = 0; ti < TPB; ++ti) {
    int b = b0 + ti;
    if (b >= ntiles) break;
    int4 ifo = tinfo[b];
    int e0 = ifo.x, nrows = ifo.y, r = ifo.z;

    bool valid = m < nrows;
    int e = valid ? (e0 + m) : e0;
    int src = sSrc[e];
    if (ug == 0) Rows[m] = valid ? sDst[e] : 0;

    if (xbf) {
      const unsigned short* xr = xb + (size_t)src * 128;
      #pragma unroll
      for (int s = 0; s < 4; ++s) {
        int u = ug * 4 + s;
        short8 pk = (short8)(short)0;
        if (valid) pk = *(const short8*)(xr + u * 8);
        *(short8*)&As[(m * 17 + u) * 8] = pk;
      }
    } else {
      const float* xr = xf + (size_t)src * 128;
      #pragma unroll
      for (int s = 0; s < 4; ++s) {
        int u = ug * 4 + s;
        float4 f0 = make_float4(0.f, 0.f, 0.f, 0.f), f1 = f0;
        if (valid) {
          f0 = *(const float4*)(xr + u * 8);
          f1 = *(const float4*)(xr + u * 8 + 4);
        }
        short8 pk;
        pk[0] = (short)f2bf(f0.x); pk[1] = (short)f2bf(f0.y);
        pk[2] = (short)f2bf(f0.z); pk[3] = (short)f2bf(f0.w);
        pk[4] = (short)f2bf(f1.x); pk[5] = (short)f2bf(f1.y);
        pk[6] = (short)f2bf(f1.z); pk[7] = (short)f2bf(f1.w);
        *(short8*)&As[(m * 17 + u) * 8] = pk;
      }
    }
    __syncthreads();

    if (r != rprev) {
      const unsigned short* wr = wT + r * 16384;
      #pragma unroll
      for (int ns = 0; ns < 2; ++ns)
        #pragma unroll
        for (int kk = 0; kk < 4; ++kk)
          bfr[ns][kk] = *(const short8*)(wr + (wave * 32 + ns * 16 + l15) * 128 + kk * 32 + q * 8);
      rprev = r;
    }

    f32x4 acc[4][2];
    #pragma unroll
    for (int ms = 0; ms < 4; ++ms)
      #pragma unroll
      for (int ns = 0; ns < 2; ++ns)
        acc[ms][ns] = (f32x4){0.f, 0.f, 0.f, 0.f};
    #pragma unroll
    for (int kk = 0; kk < 4; ++kk) {
      short8 af[4];
      #pragma unroll
      for (int ms = 0; ms < 4; ++ms)
        af[ms] = *(const short8*)&As[((ms * 16 + l15) * 17 + kk * 4 + q) * 8];
      #pragma unroll
      for (int ms = 0; ms < 4; ++ms)
        #pragma unroll
        for (int ns = 0; ns < 2; ++ns)
          acc[ms][ns] = __builtin_amdgcn_mfma_f32_16x16x32_bf16(af[ms], bfr[ns][kk], acc[ms][ns], 0, 0, 0);
    }

    __syncthreads();
    #pragma unroll
    for (int ms = 0; ms < 4; ++ms)
      #pragma unroll
      for (int reg = 0; reg < 4; ++reg) {
        int mrow = ms * 16 + q * 4 + reg;
        if (mrow < nrows) {
          float* op = out + (size_t)Rows[mrow] * 128 + wave * 32 + l15;
          unsafeAtomicAdd(op, acc[ms][0][reg]);
          unsafeAtomicAdd(op + 16, acc[ms][1][reg]);
        }
      }
    __syncthreads();
  }
}

// one 16-lane group per dst: idx-gather confined to the dst's bucket window
__global__ __launch_bounds__(256) void k_reduce(const unsigned short* __restrict__ msg,
    const int* __restrict__ dstOff, const int* __restrict__ idx,
    float* __restrict__ out)
{
  int d = blockIdx.x * 16 + (threadIdx.x >> 4);
  if (d >= NN) return;
  int sl = threadIdx.x & 15;
  int s = dstOff[d], e = dstOff[d + 1];
  const unsigned short* base = msg + (size_t)sl * 8;
  float a[8], bacc[8];
  #pragma unroll
  for (int i = 0; i < 8; ++i) { a[i] = 0.f; bacc[i] = 0.f; }
  int j = s;
  for (; j + 1 < e; j += 2) {
    size_t p0 = (size_t)idx[j] * 128;
    size_t p1 = (size_t)idx[j + 1] * 128;
    u32x4 v0 = *(const u32x4*)(base + p0);
    u32x4 v1 = *(const u32x4*)(base + p1);
    #pragma unroll
    for (int c = 0; c < 4; ++c) {
      a[2 * c]     += __builtin_bit_cast(float, v0[c] << 16);
      a[2 * c + 1] += __builtin_bit_cast(float, v0[c] & 0xffff0000u);
      bacc[2 * c]     += __builtin_bit_cast(float, v1[c] << 16);
      bacc[2 * c + 1] += __builtin_bit_cast(float, v1[c] & 0xffff0000u);
    }
  }
  if (j < e) {
    u32x4 v0 = *(const u32x4*)(base + (size_t)idx[j] * 128);
    #pragma unroll
    for (int c = 0; c < 4; ++c) {
      a[2 * c]     += __builtin_bit_cast(float, v0[c] << 16);
      a[2 * c + 1] += __builtin_bit_cast(float, v0[c] & 0xffff0000u);
    }
  }
  f32x4 w0, w1;
  w0[0] = a[0] + bacc[0]; w0[1] = a[1] + bacc[1]; w0[2] = a[2] + bacc[2]; w0[3] = a[3] + bacc[3];
  w1[0] = a[4] + bacc[4]; w1[1] = a[5] + bacc[5]; w1[2] = a[6] + bacc[6]; w1[3] = a[7] + bacc[7];
  float* op = out + (size_t)d * 128 + sl * 8;
  __builtin_nontemporal_store(w0, (f32x4*)op);
  __builtin_nontemporal_store(w1, (f32x4*)(op + 4));
}

extern "C" void kernel_launch(void* const* d_in, const int* in_sizes, int n_in,
                              void* d_out, int out_size, void* d_ws, size_t ws_size,
                              hipStream_t stream)
{
  const float* x      = (const float*)d_in[0];
  const int*   ei     = (const int*)d_in[1];
  const int*   et     = (const int*)d_in[2];
  const float* bases  = (const float*)d_in[3];
  const float* coef   = (const float*)d_in[4];
  const float* w_self = (const float*)d_in[5];
  float* out = (float*)d_out;
  char* ws = (char*)d_ws;
  unsigned short* wT = (unsigned short*)(ws + WT_OFF);
  int* meta      = (int*)(ws + META_OFF);
  int* dstHist   = (int*)(ws + DH_OFF);
  int4* tinfo    = (int4*)(ws + TI_OFF);     // aliases dstHist (dead after scan1)
  int* dstOff    = (int*)(ws + DO_OFF);
  int* dstCursor = (int*)(ws + DC_OFF);
  int* blockSums = (int*)(ws + BS_OFF);
  int* sSrc      = (int*)(ws + SSRC_OFF);
  int* idx       = (int*)(ws + IDX_OFF);
  int* sDst      = (int*)(ws + SDST_OFF);
  unsigned short* xb = (unsigned short*)(ws + XB_OFF);
  unsigned short* msg = (unsigned short*)(ws + MSG_OFF);

  const int msgmode = (ws_size >= NEED_MSG) ? 1 : 0;
  const int xbf = (msgmode || ws_size >= NEED_XB) ? 1 : 0;

  hipMemsetAsync(ws + META_OFF, 0, META_BYTES + 400000, stream);  // meta + dstHist
  k_ph<<<WGRID + (xbf ? 12500 : 0) + 256, 256, 0, stream>>>(
      bases, coef, w_self, wT, x, xb, ei, et, meta, dstHist, xbf, msgmode);
  if (msgmode) {
    k_scan1<<<SCANB, 256, 0, stream>>>(dstHist, dstOff, blockSums);
    k_scan2<<<1, 1024, 0, stream>>>(blockSums, meta, 1);
    k_scan3<<<SCANB, 256, 0, stream>>>(dstOff, blockSums, dstCursor, sSrc, idx, meta);
  } else {
    k_scan2<<<1, 1024, 0, stream>>>(blockSums, meta, 0);
    k_selfF<<<SCANB, 256, 0, stream>>>(sSrc, sDst, meta);
    hipMemsetAsync(d_out, 0, (size_t)NN * D * 4, stream);
  }
  k_scatter<<<SCATB + TIB, 256, 0, stream>>>(ei, et, meta, sSrc, sDst, dstCursor, idx, tinfo, msgmode);
  k_gemm<<<GEMMG, 256, 0, stream>>>(x, xb, wT, meta, sSrc, sDst, tinfo, msg, out, xbf, msgmode);
  if (msgmode)
    k_reduce<<<(NN + 15) / 16, 256, 0, stream>>>(msg, dstOff, idx, out);
}